// Round 4
// baseline (146.703 us; speedup 1.0000x reference)
//
#include <hip/hip_runtime.h>

// NT-Xent loss: z_i, z_j [4096,1024] f32 -> scalar f32 loss.
// loss = mean_i( log(sum_{j != i} exp(2*cos_sim(i,j))) - 2*cos_sim(i, i^1) )
//
// R4: R3's 256^2 8-phase schedule unchanged; diagonal tiles compute only the
//     upper triangle (frag/read skipping), harvested into rs (j>i) and cs
//     (j<i via symmetry, stored in unused planes (P-1)*4+{2,3}); half-diags
//     dispatched last to fill the 528-block tail (makespan 3T -> ~2T).

#define N_ROWS 8192
#define HALF_N 4096
#define DIMK   1024
#define BM     256
#define BK     64
#define NPANEL (N_ROWS / BM)   // 32
#define NSLOTS (NPANEL * 4)    // 128 partial planes
#define ITERS  (DIMK / (2 * BK))   // 8 (2 K-tiles per iteration)

typedef float        f32x4  __attribute__((ext_vector_type(4)));
typedef unsigned int u32x4  __attribute__((ext_vector_type(4)));
typedef __bf16       bf16x8 __attribute__((ext_vector_type(8)));

__device__ __forceinline__ unsigned short f32_to_bf16_rne(float f) {
    union { float f; unsigned int u; } v; v.f = f;
    unsigned int r = v.u + 0x7fffu + ((v.u >> 16) & 1u);
    return (unsigned short)(r >> 16);
}

// ---------------- Kernel 1: row L2-normalize, f32 -> bf16 --------------------
__global__ __launch_bounds__(256) void norm_rows_kernel(
    const float* __restrict__ z_i, const float* __restrict__ z_j,
    unsigned short* __restrict__ xn)
{
    const int row = blockIdx.x;
    const float* src = (row < HALF_N) ? (z_i + (size_t)row * DIMK)
                                      : (z_j + (size_t)(row - HALF_N) * DIMK);
    const int t = threadIdx.x;
    const float4 v = ((const float4*)src)[t];
    float ss = v.x * v.x + v.y * v.y + v.z * v.z + v.w * v.w;
    #pragma unroll
    for (int m = 1; m < 64; m <<= 1) ss += __shfl_xor(ss, m, 64);
    __shared__ float red[4];
    const int lane = t & 63, wave = t >> 6;
    if (lane == 0) red[wave] = ss;
    __syncthreads();
    ss = red[0] + red[1] + red[2] + red[3];
    const float rn = 1.0f / fmaxf(sqrtf(ss), 1e-8f);

    union { unsigned short s[4]; uint2 u; } pack;
    pack.s[0] = f32_to_bf16_rne(v.x * rn);
    pack.s[1] = f32_to_bf16_rne(v.y * rn);
    pack.s[2] = f32_to_bf16_rne(v.z * rn);
    pack.s[3] = f32_to_bf16_rne(v.w * rn);
    ((uint2*)(xn + (size_t)row * DIMK))[t] = pack.u;
}

// ---- Kernel 2: fused sim-GEMM (bf16 MFMA, 256^2 8-phase) + exp row sums -----
__device__ __forceinline__ bf16x8 ldfrag(const u32x4* buf, int r, int kc) {
    return __builtin_bit_cast(bf16x8, buf[r * 8 + (kc ^ (r & 7))]);
}

#define BAR() do { asm volatile("" ::: "memory"); \
                   __builtin_amdgcn_s_barrier();  \
                   asm volatile("" ::: "memory"); } while (0)
#define WAITVM(N) asm volatile("s_waitcnt vmcnt(" #N ")" ::: "memory")
#define GLDS(gp, lp) __builtin_amdgcn_global_load_lds(                          \
        (const __attribute__((address_space(1))) void*)(gp),                    \
        (__attribute__((address_space(3))) void*)(lp), 16, 0, 0)

__global__ __launch_bounds__(512, 2) void simexp_kernel(
    const unsigned short* __restrict__ xn,
    float* __restrict__ partial,   // [NSLOTS][N_ROWS]
    float* __restrict__ tgt)       // [N_ROWS]
{
    __shared__ u32x4 As[2][BM * 8];   // 2 x 32 KiB
    __shared__ u32x4 Bs[2][BM * 8];   // 2 x 32 KiB

    // Block order: [0,496) off-diag (XCD-swizzled, m204 bijective nwg=497),
    // 496 = full diag (0,0), [497,528) = half-diags 1..31 (dispatched last).
    const int orig = blockIdx.x;
    int bid;
    if (orig < 497) {
        const int q = 62, r = 1;                 // 497 = 8*62 + 1
        const int xcd = orig & 7, lin = orig >> 3;
        bid = (xcd < r ? xcd * (q + 1) : r * (q + 1) + (xcd - r) * q) + lin;
    } else {
        bid = orig;
    }
    int ip, jp;
    if (bid < 496) {            // strict upper triangle (ip < jp)
        int rem = bid; ip = 0;
        while (rem >= NPANEL - 1 - ip) { rem -= NPANEL - 1 - ip; ++ip; }
        jp = ip + 1 + rem;
    } else if (bid == 496) {
        ip = 0; jp = 0;          // full diagonal tile
    } else {
        ip = bid - 496; jp = ip; // half diagonal tiles
    }

    const int t = threadIdx.x;
    const int lane = t & 63, wave = t >> 6;
    const int wm = wave >> 2, wn = wave & 3;   // 2 x 4 wave grid
    const int rowBase = ip * BM, colBase = jp * BM;
    const int l15 = lane & 15, lhi = lane >> 4;

    const bool diag = (ip == jp);
    const bool halfdiag = diag && (ip > 0);
    // quadrant Q (rows wm*128+Q*32..+32) has any needed frag iff
    // max col_lo (wn*64+48) >= min row_lo  (frag needed <=> col_lo >= row_lo)
    bool qNeed[4];
    #pragma unroll
    for (int qq = 0; qq < 4; ++qq)
        qNeed[qq] = !halfdiag || (wn * 64 + 48 >= wm * 128 + qq * 32);
    const bool waveAlive = qNeed[0];

    // staging geometry: per STAGEU (one 128-row half-tile), thread does 2 loads
    const int r_lo = t >> 3;                         // 0..63
    const int c8e  = (((t & 7) ^ (r_lo & 7)) << 3);  // inverse-swizzled chunk

#define STAGEU(BUF, SLOT, HALF, PANROW, KTILE) do {                              \
        const unsigned short* _g0 = xn +                                         \
            (size_t)((PANROW) + (HALF) * 128 + r_lo) * DIMK + (KTILE) * BK + c8e;\
        const unsigned short* _g1 = xn +                                         \
            (size_t)((PANROW) + (HALF) * 128 + 64 + r_lo) * DIMK + (KTILE) * BK + c8e;\
        GLDS(_g0, &BUF[SLOT][(HALF) * 1024 + wave * 64]);                        \
        GLDS(_g1, &BUF[SLOT][(HALF) * 1024 + 512 + wave * 64]);                  \
    } while (0)

    f32x4 acc[8][4];
    #pragma unroll
    for (int i = 0; i < 8; ++i)
        #pragma unroll
        for (int j = 0; j < 4; ++j) {
            f32x4 z = {0.0f, 0.0f, 0.0f, 0.0f};
            acc[i][j] = z;
        }

    bf16x8 bfr[4][2];   // B frags for current K-tile
    bf16x8 af[2][2];    // A frags for current quadrant

#define LOAD_B(BP) do { if (waveAlive) { _Pragma("unroll")                       \
        for (int ni = 0; ni < 4; ++ni) {                                         \
            const int r = wn * 64 + ni * 16 + l15;                               \
            bfr[ni][0] = ldfrag(BP, r, lhi);                                     \
            bfr[ni][1] = ldfrag(BP, r, 4 + lhi);                                 \
        } } } while (0)
#define LOAD_A(AP, Q) do { if (qNeed[Q]) { _Pragma("unroll")                     \
        for (int m2 = 0; m2 < 2; ++m2) {                                         \
            const int r = wm * 128 + ((Q) * 2 + m2) * 16 + l15;                  \
            af[m2][0] = ldfrag(AP, r, lhi);                                      \
            af[m2][1] = ldfrag(AP, r, 4 + lhi);                                  \
        } } } while (0)
#define MFMA16(Q) do { if (qNeed[Q]) {                                           \
        __builtin_amdgcn_s_setprio(1);                                           \
        _Pragma("unroll")                                                        \
        for (int m2 = 0; m2 < 2; ++m2) {                                         \
            const int rowlo = wm * 128 + ((Q) * 2 + m2) * 16;                    \
            _Pragma("unroll")                                                    \
            for (int ni = 0; ni < 4; ++ni) {                                     \
                if (!halfdiag || (wn * 64 + ni * 16) >= rowlo) {                 \
                    _Pragma("unroll")                                            \
                    for (int kk = 0; kk < 2; ++kk)                               \
                        acc[(Q) * 2 + m2][ni] = __builtin_amdgcn_mfma_f32_16x16x32_bf16( \
                            af[m2][kk], bfr[ni][kk], acc[(Q) * 2 + m2][ni], 0, 0, 0); \
                }                                                                \
            }                                                                    \
        }                                                                        \
        __builtin_amdgcn_s_setprio(0);                                           \
    } } while (0)

    const u32x4* A0p = &As[0][0]; const u32x4* B0p = &Bs[0][0];
    const u32x4* A1p = &As[1][0]; const u32x4* B1p = &Bs[1][0];

    // ---- prologue: ktile0 (A+B, slot0) + ktile1 B (slot1); keep newest 4 ----
    STAGEU(As, 0, 0, rowBase, 0); STAGEU(As, 0, 1, rowBase, 0);
    STAGEU(Bs, 0, 0, colBase, 0); STAGEU(Bs, 0, 1, colBase, 0);
    STAGEU(Bs, 1, 0, colBase, 1); STAGEU(Bs, 1, 1, colBase, 1);
    WAITVM(4);
    BAR();

    for (int it = 0; it < ITERS; ++it) {
        const int kA = 2 * it;
        const bool nx = (it + 1 < ITERS);
        // ================= phases 1-4: K-tile kA (slot 0) =================
        LOAD_B(B0p); LOAD_A(A0p, 0);
        STAGEU(As, 1, 0, rowBase, kA + 1); STAGEU(As, 1, 1, rowBase, kA + 1);
        BAR(); MFMA16(0); BAR();
        LOAD_A(A0p, 1); if (nx) STAGEU(Bs, 0, 0, colBase, kA + 2);
        BAR(); MFMA16(1); BAR();
        LOAD_A(A0p, 2); if (nx) STAGEU(Bs, 0, 1, colBase, kA + 2);
        BAR(); MFMA16(2); BAR();
        LOAD_A(A0p, 3);
        BAR(); MFMA16(3);
        if (nx) { WAITVM(4); } else { WAITVM(0); }
        BAR();
        // ================= phases 5-8: K-tile kA+1 (slot 1) ===============
        LOAD_B(B1p); LOAD_A(A1p, 0);
        if (nx) { STAGEU(As, 0, 0, rowBase, kA + 2); STAGEU(As, 0, 1, rowBase, kA + 2); }
        BAR(); MFMA16(0); BAR();
        LOAD_A(A1p, 1); if (nx) STAGEU(Bs, 1, 0, colBase, kA + 3);
        BAR(); MFMA16(1); BAR();
        LOAD_A(A1p, 2); if (nx) STAGEU(Bs, 1, 1, colBase, kA + 3);
        BAR(); MFMA16(2); BAR();
        LOAD_A(A1p, 3);
        BAR(); MFMA16(3);
        if (nx) { WAITVM(4); }
        BAR();
    }
#undef STAGEU
#undef LOAD_A
#undef LOAD_B
#undef MFMA16

    // ---- epilogue ----
    // C/D layout (m89/m91): col = lane&15, row = (lane>>4)*4 + e
    const int colW = colBase + wn * 64;
    float cs[4] = {0.0f, 0.0f, 0.0f, 0.0f};
    #pragma unroll
    for (int mi = 0; mi < 8; ++mi) {
        const int rbase = rowBase + wm * 128 + mi * 16 + (lhi << 2);
        float rs[4] = {0.0f, 0.0f, 0.0f, 0.0f};
        #pragma unroll
        for (int ni = 0; ni < 4; ++ni) {
            const int gcol = colW + ni * 16 + l15;
            #pragma unroll
            for (int e = 0; e < 4; ++e) {
                const int grow = rbase + e;
                const float tv = acc[mi][ni][e] * 2.0f;     // /TEMPERATURE
                // pair (even, even+1) lives strictly-upper in diag tiles only;
                // sim symmetric -> write both rows from the one computed cell.
                if (gcol == grow + 1 && ((grow & 1) == 0)) {
                    tgt[grow] = tv; tgt[grow + 1] = tv;
                }
                const bool inc = halfdiag ? (gcol > grow) : (gcol != grow);
                const float ev = inc ? __expf(tv) : 0.0f;
                rs[e] += ev;
                cs[ni] += ev;
            }
        }
        #pragma unroll
        for (int m = 1; m < 16; m <<= 1) {
            #pragma unroll
            for (int e = 0; e < 4; ++e) rs[e] += __shfl_xor(rs[e], m, 64);
        }
        if (l15 == 0) {
            float* dst = partial + (size_t)(jp * 4 + wn) * N_ROWS + rbase;
            dst[0] = rs[0]; dst[1] = rs[1]; dst[2] = rs[2]; dst[3] = rs[3];
        }
    }
    if (!diag || halfdiag) {
        #pragma unroll
        for (int ni = 0; ni < 4; ++ni) {
            cs[ni] += __shfl_xor(cs[ni], 16, 64);
            cs[ni] += __shfl_xor(cs[ni], 32, 64);
        }
        if (lhi == 0) {
            // off-diag: plane ip*4+wm (rows of panel jp, cols panel ip)
            // half-diag: planes (ip-1)*4+{2,3} — unused for rows of panel ip
            const int plane = (!diag) ? (ip * 4 + wm) : ((ip - 1) * 4 + 2 + wm);
            float* dst = partial + (size_t)plane * N_ROWS;
            #pragma unroll
            for (int ni = 0; ni < 4; ++ni)
                dst[colW + ni * 16 + l15] = cs[ni];
        }
    }
}

// ------------- Kernel 3: per-row LSE - target logit --------------------------
// Row x in panel P sums: planes q*4+{0..3} for q >= P (rs), planes q*4+{0,1}
// for q < P (off-diag cs), and planes (P-1)*4+{2,3} (diag cs) when P >= 1.
__global__ __launch_bounds__(256) void row_term_kernel(
    const float* __restrict__ partial, const float* __restrict__ tgt,
    float* __restrict__ terms)
{
    const int row = blockIdx.x * 256 + threadIdx.x;
    const int P = row >> 8;
    float s = 0.0f;
    for (int q = 0; q < NPANEL; ++q) {
        const float* base = partial + (size_t)q * 4 * N_ROWS + row;
        s += base[0] + base[(size_t)N_ROWS];
        if (q >= P) s += base[(size_t)2 * N_ROWS] + base[(size_t)3 * N_ROWS];
    }
    if (P >= 1) {
        const float* b2 = partial + ((size_t)(P - 1) * 4 + 2) * N_ROWS + row;
        s += b2[0] + b2[(size_t)N_ROWS];
    }
    terms[row] = logf(s) - tgt[row];
}

// ------------- Kernel 4: mean over rows --------------------------------------
__global__ __launch_bounds__(256) void loss_kernel(
    const float* __restrict__ terms, float* __restrict__ out)
{
    const int t = threadIdx.x;
    float s = 0.0f;
    for (int i = t; i < N_ROWS; i += 256) s += terms[i];
    #pragma unroll
    for (int m = 1; m < 64; m <<= 1) s += __shfl_xor(s, m, 64);
    __shared__ float red[4];
    if ((t & 63) == 0) red[t >> 6] = s;
    __syncthreads();
    if (t == 0) out[0] = (red[0] + red[1] + red[2] + red[3]) * (1.0f / N_ROWS);
}

extern "C" void kernel_launch(void* const* d_in, const int* in_sizes, int n_in,
                              void* d_out, int out_size, void* d_ws, size_t ws_size,
                              hipStream_t stream)
{
    const float* z_i = (const float*)d_in[0];
    const float* z_j = (const float*)d_in[1];
    float* out = (float*)d_out;

    unsigned short* xn = (unsigned short*)d_ws;                         // 16 MiB bf16
    float* partial = (float*)((char*)d_ws + (size_t)N_ROWS * DIMK * 2); // 4 MiB
    float* tgt     = partial + (size_t)NSLOTS * N_ROWS;                 // 32 KiB
    float* terms   = tgt + N_ROWS;                                      // 32 KiB

    const int nblk = NPANEL * (NPANEL + 1) / 2;   // 528

    norm_rows_kernel<<<N_ROWS, 256, 0, stream>>>(z_i, z_j, xn);
    simexp_kernel<<<nblk, 512, 0, stream>>>(xn, partial, tgt);
    row_term_kernel<<<N_ROWS / 256, 256, 0, stream>>>(partial, tgt, terms);
    loss_kernel<<<1, 256, 0, stream>>>(terms, out);
}

// Round 5
// 136.253 us; speedup vs baseline: 1.0767x; 1.0767x over previous
//
#include <hip/hip_runtime.h>

// NT-Xent loss: z_i, z_j [4096,1024] f32 -> scalar f32 loss.
// loss = mean_i( log(sum_{j != i} exp(2*cos_sim(i,j))) - 2*cos_sim(i, i^1) )
//
// R5: revert R4 diag-halving (regressed). R3 structure + m201-faithful stage
//     spreading: exactly one half-tile (2 global_load_lds) per phase, 12 vmem
//     ops in flight, vmcnt(4) at ph4/ph8 draining exactly the needed 8.

#define N_ROWS 8192
#define HALF_N 4096
#define DIMK   1024
#define BM     256
#define BK     64
#define NPANEL (N_ROWS / BM)   // 32
#define NSLOTS (NPANEL * 4)    // 128 partial planes
#define ITERS  (DIMK / (2 * BK))   // 8 (2 K-tiles per iteration)

typedef float        f32x4  __attribute__((ext_vector_type(4)));
typedef unsigned int u32x4  __attribute__((ext_vector_type(4)));
typedef __bf16       bf16x8 __attribute__((ext_vector_type(8)));

__device__ __forceinline__ unsigned short f32_to_bf16_rne(float f) {
    union { float f; unsigned int u; } v; v.f = f;
    unsigned int r = v.u + 0x7fffu + ((v.u >> 16) & 1u);
    return (unsigned short)(r >> 16);
}

// ---------------- Kernel 1: row L2-normalize, f32 -> bf16 --------------------
__global__ __launch_bounds__(256) void norm_rows_kernel(
    const float* __restrict__ z_i, const float* __restrict__ z_j,
    unsigned short* __restrict__ xn)
{
    const int row = blockIdx.x;
    const float* src = (row < HALF_N) ? (z_i + (size_t)row * DIMK)
                                      : (z_j + (size_t)(row - HALF_N) * DIMK);
    const int t = threadIdx.x;
    const float4 v = ((const float4*)src)[t];
    float ss = v.x * v.x + v.y * v.y + v.z * v.z + v.w * v.w;
    #pragma unroll
    for (int m = 1; m < 64; m <<= 1) ss += __shfl_xor(ss, m, 64);
    __shared__ float red[4];
    const int lane = t & 63, wave = t >> 6;
    if (lane == 0) red[wave] = ss;
    __syncthreads();
    ss = red[0] + red[1] + red[2] + red[3];
    const float rn = 1.0f / fmaxf(sqrtf(ss), 1e-8f);

    union { unsigned short s[4]; uint2 u; } pack;
    pack.s[0] = f32_to_bf16_rne(v.x * rn);
    pack.s[1] = f32_to_bf16_rne(v.y * rn);
    pack.s[2] = f32_to_bf16_rne(v.z * rn);
    pack.s[3] = f32_to_bf16_rne(v.w * rn);
    ((uint2*)(xn + (size_t)row * DIMK))[t] = pack.u;
}

// ---- Kernel 2: fused sim-GEMM (bf16 MFMA, 256^2 8-phase) + exp row sums -----
__device__ __forceinline__ bf16x8 ldfrag(const u32x4* buf, int r, int kc) {
    return __builtin_bit_cast(bf16x8, buf[r * 8 + (kc ^ (r & 7))]);
}

#define BAR() do { asm volatile("" ::: "memory"); \
                   __builtin_amdgcn_s_barrier();  \
                   asm volatile("" ::: "memory"); } while (0)
#define WAITVM(N) asm volatile("s_waitcnt vmcnt(" #N ")" ::: "memory")
#define GLDS(gp, lp) __builtin_amdgcn_global_load_lds(                          \
        (const __attribute__((address_space(1))) void*)(gp),                    \
        (__attribute__((address_space(3))) void*)(lp), 16, 0, 0)

__global__ __launch_bounds__(512, 2) void simexp_kernel(
    const unsigned short* __restrict__ xn,
    float* __restrict__ partial,   // [NSLOTS][N_ROWS]
    float* __restrict__ tgt)       // [N_ROWS]
{
    __shared__ u32x4 As[2][BM * 8];   // 2 x 32 KiB
    __shared__ u32x4 Bs[2][BM * 8];   // 2 x 32 KiB

    // bijective XCD swizzle (m204): nwg=528 = 8*66, q=66, r=0
    const int orig = blockIdx.x;
    const int bid  = (orig & 7) * 66 + (orig >> 3);

    // decode (ip, jp) with ip <= jp
    int rem = bid, ip = 0;
    while (rem >= NPANEL - ip) { rem -= NPANEL - ip; ++ip; }
    const int jp = ip + rem;

    const int t = threadIdx.x;
    const int lane = t & 63, wave = t >> 6;
    const int wm = wave >> 2, wn = wave & 3;   // 2 x 4 wave grid
    const int rowBase = ip * BM, colBase = jp * BM;
    const int l15 = lane & 15, lhi = lane >> 4;

    // staging geometry: per STAGEU (one 128-row half-tile), thread does 2 loads
    const int r_lo = t >> 3;                         // 0..63
    const int c8e  = (((t & 7) ^ (r_lo & 7)) << 3);  // inverse-swizzled chunk

#define STAGEU(BUF, SLOT, HALF, PANROW, KTILE) do {                              \
        const unsigned short* _g0 = xn +                                         \
            (size_t)((PANROW) + (HALF) * 128 + r_lo) * DIMK + (KTILE) * BK + c8e;\
        const unsigned short* _g1 = xn +                                         \
            (size_t)((PANROW) + (HALF) * 128 + 64 + r_lo) * DIMK + (KTILE) * BK + c8e;\
        GLDS(_g0, &BUF[SLOT][(HALF) * 1024 + wave * 64]);                        \
        GLDS(_g1, &BUF[SLOT][(HALF) * 1024 + 512 + wave * 64]);                  \
    } while (0)

    f32x4 acc[8][4];
    #pragma unroll
    for (int i = 0; i < 8; ++i)
        #pragma unroll
        for (int j = 0; j < 4; ++j) {
            f32x4 z = {0.0f, 0.0f, 0.0f, 0.0f};
            acc[i][j] = z;
        }

    bf16x8 bfr[4][2];   // B frags for current K-tile
    bf16x8 af[2][2];    // A frags for current quadrant

#define LOAD_B(BP) do { _Pragma("unroll")                                        \
        for (int ni = 0; ni < 4; ++ni) {                                         \
            const int r = wn * 64 + ni * 16 + l15;                               \
            bfr[ni][0] = ldfrag(BP, r, lhi);                                     \
            bfr[ni][1] = ldfrag(BP, r, 4 + lhi);                                 \
        } } while (0)
#define LOAD_A(AP, Q) do { _Pragma("unroll")                                     \
        for (int m2 = 0; m2 < 2; ++m2) {                                         \
            const int r = wm * 128 + ((Q) * 2 + m2) * 16 + l15;                  \
            af[m2][0] = ldfrag(AP, r, lhi);                                      \
            af[m2][1] = ldfrag(AP, r, 4 + lhi);                                  \
        } } while (0)
#define MFMA16(Q) do {                                                           \
        __builtin_amdgcn_s_setprio(1);                                           \
        _Pragma("unroll")                                                        \
        for (int m2 = 0; m2 < 2; ++m2)                                           \
            _Pragma("unroll")                                                    \
            for (int ni = 0; ni < 4; ++ni)                                       \
                _Pragma("unroll")                                                \
                for (int kk = 0; kk < 2; ++kk)                                   \
                    acc[(Q) * 2 + m2][ni] = __builtin_amdgcn_mfma_f32_16x16x32_bf16( \
                        af[m2][kk], bfr[ni][kk], acc[(Q) * 2 + m2][ni], 0, 0, 0);\
        __builtin_amdgcn_s_setprio(0);                                           \
    } while (0)

    const u32x4* A0p = &As[0][0]; const u32x4* B0p = &Bs[0][0];
    const u32x4* A1p = &As[1][0]; const u32x4* B1p = &Bs[1][0];

    // ---- prologue: S0 (A+B, ktile0) + S1.B (ktile1); keep S1.B in flight ----
    STAGEU(As, 0, 0, rowBase, 0); STAGEU(As, 0, 1, rowBase, 0);
    STAGEU(Bs, 0, 0, colBase, 0); STAGEU(Bs, 0, 1, colBase, 0);
    STAGEU(Bs, 1, 0, colBase, 1); STAGEU(Bs, 1, 1, colBase, 1);
    WAITVM(4);
    BAR();

    for (int it = 0; it < ITERS; ++it) {
        const int kA = 2 * it;
        const bool nx = (it + 1 < ITERS);
        // ============ phases 1-4: K-tile kA (slot 0); 1 half-tile stage each
        // ph1: S1.A half0 for ktile kA+1 (S1.A last read: prev ph8)
        LOAD_B(B0p); LOAD_A(A0p, 0);
        STAGEU(As, 1, 0, rowBase, kA + 1);
        BAR(); MFMA16(0); BAR();
        // ph2: S1.A half1
        LOAD_A(A0p, 1);
        STAGEU(As, 1, 1, rowBase, kA + 1);
        BAR(); MFMA16(1); BAR();
        // ph3: S0.B half0 for ktile kA+2 (S0.B last read: ph1)
        LOAD_A(A0p, 2);
        if (nx) STAGEU(Bs, 0, 0, colBase, kA + 2);
        BAR(); MFMA16(2); BAR();
        // ph4: S0.B half1; drain prev-ph7/8 (S1.B) + ph1/2 (S1.A) -> S1 ready
        LOAD_A(A0p, 3);
        if (nx) STAGEU(Bs, 0, 1, colBase, kA + 2);
        BAR(); MFMA16(3);
        if (nx) { WAITVM(4); } else { WAITVM(0); }
        BAR();
        // ============ phases 5-8: K-tile kA+1 (slot 1) ====================
        // ph5: S0.A half0 for ktile kA+2 (S0.A last read: ph4)
        LOAD_B(B1p); LOAD_A(A1p, 0);
        if (nx) STAGEU(As, 0, 0, rowBase, kA + 2);
        BAR(); MFMA16(0); BAR();
        // ph6: S0.A half1
        LOAD_A(A1p, 1);
        if (nx) STAGEU(As, 0, 1, rowBase, kA + 2);
        BAR(); MFMA16(1); BAR();
        // ph7: S1.B half0 for ktile kA+3 (S1.B last read: ph5)
        LOAD_A(A1p, 2);
        if (nx) STAGEU(Bs, 1, 0, colBase, kA + 3);
        BAR(); MFMA16(2); BAR();
        // ph8: S1.B half1; drain ph3-6 (S0.B + S0.A) -> S0 ready for next ph1
        LOAD_A(A1p, 3);
        if (nx) STAGEU(Bs, 1, 1, colBase, kA + 3);
        BAR(); MFMA16(3);
        if (nx) { WAITVM(4); }
        BAR();
    }
#undef STAGEU
#undef LOAD_A
#undef LOAD_B
#undef MFMA16

    // ---- epilogue: logits, diag mask, target capture, per-row exp sums ----
    // C/D layout (m89/m91): col = lane&15, row = (lane>>4)*4 + e
    const int colW = colBase + wn * 64;
    float cs[4] = {0.0f, 0.0f, 0.0f, 0.0f};
    #pragma unroll
    for (int mi = 0; mi < 8; ++mi) {
        const int rbase = rowBase + wm * 128 + mi * 16 + (lhi << 2);
        float rs[4] = {0.0f, 0.0f, 0.0f, 0.0f};
        #pragma unroll
        for (int ni = 0; ni < 4; ++ni) {
            const int gcol = colW + ni * 16 + l15;
            #pragma unroll
            for (int e = 0; e < 4; ++e) {
                const int grow = rbase + e;
                const float tv = acc[mi][ni][e] * 2.0f;     // /TEMPERATURE
                if (gcol == (grow ^ 1)) tgt[grow] = tv;     // diag blocks only
                const float ev = (gcol == grow) ? 0.0f : __expf(tv);
                rs[e] += ev;
                cs[ni] += ev;
            }
        }
        #pragma unroll
        for (int m = 1; m < 16; m <<= 1) {
            #pragma unroll
            for (int e = 0; e < 4; ++e) rs[e] += __shfl_xor(rs[e], m, 64);
        }
        if (l15 == 0) {
            float* dst = partial + (size_t)(jp * 4 + wn) * N_ROWS + rbase;
            dst[0] = rs[0]; dst[1] = rs[1]; dst[2] = rs[2]; dst[3] = rs[3];
        }
    }
    if (ip != jp) {
        // column sums -> rows of panel jp, summed over this block's wm-half rows
        #pragma unroll
        for (int ni = 0; ni < 4; ++ni) {
            cs[ni] += __shfl_xor(cs[ni], 16, 64);
            cs[ni] += __shfl_xor(cs[ni], 32, 64);
        }
        if (lhi == 0) {
            float* dst = partial + (size_t)(ip * 4 + wm) * N_ROWS;
            #pragma unroll
            for (int ni = 0; ni < 4; ++ni)
                dst[colW + ni * 16 + l15] = cs[ni];
        }
    }
}

// ------------- Kernel 3: per-row LSE - target logit --------------------------
// Valid planes for row in panel P: {q*4+s, s<4 : q>=P} U {q*4+s, s<2 : q<P}
__global__ __launch_bounds__(256) void row_term_kernel(
    const float* __restrict__ partial, const float* __restrict__ tgt,
    float* __restrict__ terms)
{
    const int row = blockIdx.x * 256 + threadIdx.x;
    const int P = row >> 8;
    float s = 0.0f;
    for (int q = 0; q < NPANEL; ++q) {
        const float* base = partial + (size_t)q * 4 * N_ROWS + row;
        s += base[0] + base[(size_t)N_ROWS];
        if (q >= P) s += base[(size_t)2 * N_ROWS] + base[(size_t)3 * N_ROWS];
    }
    terms[row] = logf(s) - tgt[row];
}

// ------------- Kernel 4: mean over rows --------------------------------------
__global__ __launch_bounds__(256) void loss_kernel(
    const float* __restrict__ terms, float* __restrict__ out)
{
    const int t = threadIdx.x;
    float s = 0.0f;
    for (int i = t; i < N_ROWS; i += 256) s += terms[i];
    #pragma unroll
    for (int m = 1; m < 64; m <<= 1) s += __shfl_xor(s, m, 64);
    __shared__ float red[4];
    if ((t & 63) == 0) red[t >> 6] = s;
    __syncthreads();
    if (t == 0) out[0] = (red[0] + red[1] + red[2] + red[3]) * (1.0f / N_ROWS);
}

extern "C" void kernel_launch(void* const* d_in, const int* in_sizes, int n_in,
                              void* d_out, int out_size, void* d_ws, size_t ws_size,
                              hipStream_t stream)
{
    const float* z_i = (const float*)d_in[0];
    const float* z_j = (const float*)d_in[1];
    float* out = (float*)d_out;

    unsigned short* xn = (unsigned short*)d_ws;                         // 16 MiB bf16
    float* partial = (float*)((char*)d_ws + (size_t)N_ROWS * DIMK * 2); // 4 MiB
    float* tgt     = partial + (size_t)NSLOTS * N_ROWS;                 // 32 KiB
    float* terms   = tgt + N_ROWS;                                      // 32 KiB

    const int ntri = NPANEL * (NPANEL + 1) / 2;   // 528 blocks

    norm_rows_kernel<<<N_ROWS, 256, 0, stream>>>(z_i, z_j, xn);
    simexp_kernel<<<ntri, 512, 0, stream>>>(xn, partial, tgt);
    row_term_kernel<<<N_ROWS / 256, 256, 0, stream>>>(partial, tgt, terms);
    loss_kernel<<<1, 256, 0, stream>>>(terms, out);
}

// Round 6
// 132.235 us; speedup vs baseline: 1.1094x; 1.0304x over previous
//
#include <hip/hip_runtime.h>

// NT-Xent loss: z_i, z_j [4096,1024] f32 -> scalar f32 loss.
// loss = mean_i( log(sum_{j != i} exp(2*cos_sim(i,j))) - 2*cos_sim(i, i^1) )
//
// R6: MX-fp8 (e4m3, scales=1.0) 32x32x64 scaled MFMA; xn pre-scaled by 16
//     (power of 2, lossless to rescale; logits = acc * 2/256).
//     Grid: 1056 tiles of 256 rows x 128 cols covering the strict upper
//     triangle exactly once (tile (rt,jc) exists iff jc >= 2*rt).
//     4 waves/block (128x64 wave-tile, acc 8 x f32x16), LDS 48 KiB
//     double-buffered -> 2 blocks/CU for cross-block MFMA/LDS overlap.
//     rs = row sums (upper cells), cs = mirrored column sums.

#define N_ROWS 8192
#define HALF_N 4096
#define DIMK   1024
#define KTILES 16          // 1024 / 64
#define NJC    64          // 128-wide column panels
#define NTILES 1056        // sum_{jc} (jc/2 + 1)
#define LOGIT_SCALE (2.0f / 256.0f)   // /TEMPERATURE, undo 16*16 fp8 pre-scale

typedef float        f32x16 __attribute__((ext_vector_type(16)));
typedef int          i32x8  __attribute__((ext_vector_type(8)));
typedef unsigned int u32x4  __attribute__((ext_vector_type(4)));

// ---------------- fp8 e4m3 (OCP) conversion, RNE, software ------------------
__device__ __forceinline__ unsigned int f32_to_e4m3(float f) {
    unsigned int b = __float_as_uint(f);
    unsigned int s = (b >> 24) & 0x80u;
    float a = fabsf(f);
    if (a < 0.0009765625f) return s;                  // < 2^-10 -> 0
    if (a < 0.015625f) {                              // subnormal: m * 2^-9
        int q = (int)rintf(a * 512.0f);               // 0..8 (8 -> min normal)
        return s | (unsigned int)q;
    }
    if (a >= 464.0f) return s | 0x7Eu;                // clamp to 448
    int e = (int)((b >> 23) & 0xFF) - 127;            // [-6, 8]
    unsigned int man = b & 0x7FFFFFu;
    unsigned int r = man + 0x7FFFFu + ((man >> 20) & 1u);  // RNE to 3 bits
    unsigned int m8 = r >> 20;
    if (m8 == 8u) { m8 = 0u; ++e; if (e > 8) return s | 0x7Eu; }
    return s | ((unsigned int)(e + 7) << 3) | m8;
}

// ---------------- Kernel 1: row L2-normalize, f32 -> fp8*16 ------------------
// one wave per row; 4 waves per block
__global__ __launch_bounds__(256) void norm_rows_kernel(
    const float* __restrict__ z_i, const float* __restrict__ z_j,
    unsigned int* __restrict__ xn8)   // [8192][256] u32 (=1024 fp8)
{
    const int wave = threadIdx.x >> 6, lane = threadIdx.x & 63;
    const int row = blockIdx.x * 4 + wave;
    const float* src = (row < HALF_N) ? (z_i + (size_t)row * DIMK)
                                      : (z_j + (size_t)(row - HALF_N) * DIMK);
    float4 v[4];
    float ss = 0.0f;
    #pragma unroll
    for (int i = 0; i < 4; ++i) {
        v[i] = ((const float4*)src)[i * 64 + lane];
        ss += v[i].x * v[i].x + v[i].y * v[i].y + v[i].z * v[i].z + v[i].w * v[i].w;
    }
    #pragma unroll
    for (int m = 1; m < 64; m <<= 1) ss += __shfl_xor(ss, m, 64);
    const float rn = 16.0f / fmaxf(sqrtf(ss), 1e-8f);   // x16 fp8 pre-scale

    unsigned int* dst = xn8 + (size_t)row * (DIMK / 4);
    #pragma unroll
    for (int i = 0; i < 4; ++i) {
        unsigned int p = f32_to_e4m3(v[i].x * rn)
                       | (f32_to_e4m3(v[i].y * rn) << 8)
                       | (f32_to_e4m3(v[i].z * rn) << 16)
                       | (f32_to_e4m3(v[i].w * rn) << 24);
        dst[i * 64 + lane] = p;
    }
}

// ---- Kernel 2: fused sim-GEMM (MX-fp8 32x32x64) + exp row/col sums ----------
#define BAR() do { asm volatile("" ::: "memory"); \
                   __builtin_amdgcn_s_barrier();  \
                   asm volatile("" ::: "memory"); } while (0)
#define WAITVM0() asm volatile("s_waitcnt vmcnt(0)" ::: "memory")
#define GLDS(gp, lp) __builtin_amdgcn_global_load_lds(                          \
        (const __attribute__((address_space(1))) void*)(gp),                    \
        (__attribute__((address_space(3))) void*)(lp), 16, 0, 0)

// LDS chunk placement (16B units): row r (64B = 4 chunks c), stored at
// unit (r>>3)*32 + slot, slot = quad | (c<<3), quad = ((r&3)^c) | (r&4).
// Bijective; ds_read_b128 of 32 rows x fixed c is bank-uniform (8 quads x 4).
__device__ __forceinline__ int lds_unit(int r, int c) {
    return ((r >> 3) << 5) + ((((r & 3) ^ c) | (r & 4)) | (c << 3));
}

__global__ __launch_bounds__(256, 2) void simexp_kernel(
    const unsigned char* __restrict__ xn8,
    float* __restrict__ rs,     // [128][N_ROWS] planes: jc*2 + wn
    float* __restrict__ cs,     // [64][N_ROWS]  planes: rt*2 + wm
    float* __restrict__ tgt)    // [N_ROWS]
{
    __shared__ u32x4 Abuf[2][1024];   // 2 x 16 KiB (256 rows x 4 chunks)
    __shared__ u32x4 Bbuf[2][512];    // 2 x  8 KiB (128 rows x 4 chunks)

    // bijective XCD swizzle: 1056 = 8 * 132
    const int orig = blockIdx.x;
    const int bid  = (orig & 7) * 132 + (orig >> 3);

    // decode (rt, jc): tiles ordered jc-major, rt = 0..jc/2
    int rem = bid, jc = 0;
    for (;;) { const int cnt = (jc >> 1) + 1; if (rem < cnt) break; rem -= cnt; ++jc; }
    const int rt = rem;

    const int t = threadIdx.x;
    const int lane = t & 63, wave = t >> 6;
    const int wm = wave >> 1, wn = wave & 1;     // 2x2 wave grid
    const int rowBase = rt * 256, colBase = jc * 128;
    const int l31 = lane & 31, h = lane >> 5;

    f32x16 acc[4][2];
    #pragma unroll
    for (int i = 0; i < 4; ++i)
        #pragma unroll
        for (int j = 0; j < 2; ++j)
            #pragma unroll
            for (int v = 0; v < 16; ++v) acc[i][j][v] = 0.0f;

    // stage: thread t writes 16B unit gi; inverse-map gi -> (row, chunk)
#define STAGE_TILE(SLOT, KT) do {                                                \
        _Pragma("unroll")                                                        \
        for (int s_ = 0; s_ < 4; ++s_) {                                         \
            const int gi = s_ * 256 + t;                                         \
            const int c_ = (gi >> 3) & 3, qd = gi & 7;                           \
            const int rl = ((gi >> 5) << 3) | (qd & 4) | ((qd & 3) ^ c_);        \
            const unsigned char* g = xn8 +                                       \
                (size_t)(rowBase + rl) * DIMK + (KT) * 64 + c_ * 16;             \
            GLDS(g, &Abuf[SLOT][s_ * 256 + wave * 64]);                          \
        }                                                                        \
        _Pragma("unroll")                                                        \
        for (int s_ = 0; s_ < 2; ++s_) {                                         \
            const int gi = s_ * 256 + t;                                         \
            const int c_ = (gi >> 3) & 3, qd = gi & 7;                           \
            const int rl = ((gi >> 5) << 3) | (qd & 4) | ((qd & 3) ^ c_);        \
            const unsigned char* g = xn8 +                                       \
                (size_t)(colBase + rl) * DIMK + (KT) * 64 + c_ * 16;             \
            GLDS(g, &Bbuf[SLOT][s_ * 256 + wave * 64]);                          \
        }                                                                        \
    } while (0)

    // prologue: tile 0 into slot 0
    STAGE_TILE(0, 0);
    WAITVM0();
    BAR();

    int slot = 0;
    for (int kt = 0; kt < KTILES; ++kt) {
        const bool nx = (kt + 1 < KTILES);
        if (nx) STAGE_TILE(slot ^ 1, kt + 1);

        // fragment reads: lane -> row l31 of frag, k-half h (c = 2h, 2h+1)
        union Frag { u32x4 q[2]; i32x8 v; };
        i32x8 af[4], bf[2];
        #pragma unroll
        for (int fi = 0; fi < 4; ++fi) {
            const int r = wm * 128 + fi * 32 + l31;
            Frag fa;
            fa.q[0] = Abuf[slot][lds_unit(r, 2 * h)];
            fa.q[1] = Abuf[slot][lds_unit(r, 2 * h + 1)];
            af[fi] = fa.v;
        }
        #pragma unroll
        for (int cf = 0; cf < 2; ++cf) {
            const int r = wn * 64 + cf * 32 + l31;
            Frag fb;
            fb.q[0] = Bbuf[slot][lds_unit(r, 2 * h)];
            fb.q[1] = Bbuf[slot][lds_unit(r, 2 * h + 1)];
            bf[cf] = fb.v;
        }

        __builtin_amdgcn_s_setprio(1);
        #pragma unroll
        for (int fi = 0; fi < 4; ++fi)
            #pragma unroll
            for (int cf = 0; cf < 2; ++cf)
                acc[fi][cf] = __builtin_amdgcn_mfma_scale_f32_32x32x64_f8f6f4(
                    af[fi], bf[cf], acc[fi][cf], 0, 0,
                    0, 0x7F7F7F7F, 0, 0x7F7F7F7F);   // fmt=fp8, scales=1.0
        __builtin_amdgcn_s_setprio(0);

        if (nx) WAITVM0();
        BAR();
        slot ^= 1;
    }
#undef STAGE_TILE

    // ---- epilogue ----
    // C/D 32x32 layout (m74/m101): col = lane&31, row = (v&3)+8*(v>>2)+4*(lane>>5)
    float cspart[2] = {0.0f, 0.0f};
    #pragma unroll
    for (int fi = 0; fi < 4; ++fi) {
        float rpart[16];
        #pragma unroll
        for (int v = 0; v < 16; ++v) rpart[v] = 0.0f;
        #pragma unroll
        for (int cf = 0; cf < 2; ++cf) {
            const int gcol = colBase + wn * 64 + cf * 32 + l31;
            #pragma unroll
            for (int v = 0; v < 16; ++v) {
                const int grow = rowBase + wm * 128 + fi * 32
                               + (v & 3) + 8 * (v >> 2) + 4 * h;
                const float tv = acc[fi][cf][v] * LOGIT_SCALE;
                if (gcol == grow + 1 && ((grow & 1) == 0)) {
                    tgt[grow] = tv; tgt[grow + 1] = tv;   // sim symmetric
                }
                const float ev = (gcol > grow) ? __expf(tv) : 0.0f;
                rpart[v] += ev;
                cspart[cf] += ev;
            }
        }
        // row sums: reduce over the 32 columns (lanes sharing l>>5)
        #pragma unroll
        for (int m = 1; m < 32; m <<= 1) {
            #pragma unroll
            for (int v = 0; v < 16; ++v) rpart[v] += __shfl_xor(rpart[v], m, 64);
        }
        if (l31 == 0) {
            float* dst = rs + (size_t)(jc * 2 + wn) * N_ROWS;
            #pragma unroll
            for (int v = 0; v < 16; ++v)
                dst[rowBase + wm * 128 + fi * 32 + (v & 3) + 8 * (v >> 2) + 4 * h]
                    = rpart[v];
        }
    }
    // column sums (mirror): combine lane halves, lanes 0-31 write
    #pragma unroll
    for (int cf = 0; cf < 2; ++cf) {
        cspart[cf] += __shfl_xor(cspart[cf], 32, 64);
        if (lane < 32)
            cs[(size_t)(rt * 2 + wm) * N_ROWS + colBase + wn * 64 + cf * 32 + l31]
                = cspart[cf];
    }
}

// ------------- Kernel 3: per-row LSE - target logit --------------------------
// row x: rs planes jc*2+{0,1} for jc >= 2*(x>>8); cs planes rt*2+{0,1} for
// rt <= (x>>7)/2  (exactly the tiles that exist for this row/col).
__global__ __launch_bounds__(256) void row_term_kernel(
    const float* __restrict__ rs, const float* __restrict__ cs,
    const float* __restrict__ tgt, float* __restrict__ terms)
{
    const int row = blockIdx.x * 256 + threadIdx.x;
    const int P = row >> 8, jcx = row >> 7;
    float s = 0.0f;
    for (int jc = 2 * P; jc < NJC; ++jc) {
        const float* b = rs + (size_t)(jc * 2) * N_ROWS + row;
        s += b[0] + b[N_ROWS];
    }
    for (int rt = 0; rt <= (jcx >> 1); ++rt) {
        const float* b = cs + (size_t)(rt * 2) * N_ROWS + row;
        s += b[0] + b[N_ROWS];
    }
    terms[row] = logf(s) - tgt[row];
}

// ------------- Kernel 4: mean over rows --------------------------------------
__global__ __launch_bounds__(256) void loss_kernel(
    const float* __restrict__ terms, float* __restrict__ out)
{
    const int t = threadIdx.x;
    float s = 0.0f;
    for (int i = t; i < N_ROWS; i += 256) s += terms[i];
    #pragma unroll
    for (int m = 1; m < 64; m <<= 1) s += __shfl_xor(s, m, 64);
    __shared__ float red[4];
    if ((t & 63) == 0) red[t >> 6] = s;
    __syncthreads();
    if (t == 0) out[0] = (red[0] + red[1] + red[2] + red[3]) * (1.0f / N_ROWS);
}

extern "C" void kernel_launch(void* const* d_in, const int* in_sizes, int n_in,
                              void* d_out, int out_size, void* d_ws, size_t ws_size,
                              hipStream_t stream)
{
    const float* z_i = (const float*)d_in[0];
    const float* z_j = (const float*)d_in[1];
    float* out = (float*)d_out;

    // workspace layout
    unsigned char* xn8 = (unsigned char*)d_ws;                        // 8 MiB fp8
    float* rs    = (float*)(xn8 + (size_t)N_ROWS * DIMK);             // 4 MiB
    float* cs    = rs + (size_t)128 * N_ROWS;                         // 2 MiB
    float* tgt   = cs + (size_t)64 * N_ROWS;                          // 32 KiB
    float* terms = tgt + N_ROWS;                                      // 32 KiB

    norm_rows_kernel<<<N_ROWS / 4, 256, 0, stream>>>(z_i, z_j, (unsigned int*)xn8);
    simexp_kernel<<<NTILES, 256, 0, stream>>>(xn8, rs, cs, tgt);
    row_term_kernel<<<N_ROWS / 256, 256, 0, stream>>>(rs, cs, tgt, terms);
    loss_kernel<<<1, 256, 0, stream>>>(terms, out);
}